// Round 1
// baseline (97.325 us; speedup 1.0000x reference)
//
#include <hip/hip_runtime.h>
#include <math.h>

// DiagonalSSMKernel: out[d,h,l] = 2*Re( sum_n scaled_c[d,h,n] * exp(dt[h]*a[h,n]*l) )
// H=1024, N=32 poles, L=4096, 2 directions. Output fp32, 33.5 MB.
//
// Strategy: one block per h. Per-pole constants (z^256, scaled_c, rates) are
// computed once by lanes 0..31 into LDS. Thread t covers l = t + 256*j,
// j in [0,16): start w = exp(da*t) via one exp+sincos per pole (phase small,
// t<256), then geometric recurrence w *= z^256 — 8 VALU ops per (pole, j).
// Stores are lane-contiguous (l = t + 256j) -> fully coalesced.

constexpr int H     = 1024;
constexpr int NP    = 32;
constexpr int L     = 4096;
constexpr int BLOCK = 256;
constexpr int CHUNK = 16;   // BLOCK * CHUNK == L

constexpr float INV2PI = 0.15915494309189535f;
constexpr float TWOPI  = 6.283185307179586f;

__global__ __launch_bounds__(BLOCK)
void ssm_vand_kernel(const float* __restrict__ log_dt,
                     const float* __restrict__ log_a_real,
                     const float* __restrict__ a_imag,
                     const float* __restrict__ coeffs,
                     float* __restrict__ out)
{
    const int h = blockIdx.x;
    const int t = threadIdx.x;

    // pole[2n+0] = {Re(da), phase rate (rev per l), Re(z^256), Im(z^256)}
    // pole[2n+1] = {sr0, si0, sr1, si1}  (scaled_c for dir 0 and 1)
    __shared__ float4 pole[NP * 2];

    if (t < NP) {
        const int n = t;
        const float dt  = expf(log_dt[h]);
        const float ar  = -expf(log_a_real[h * NP + n]);
        const float ai  = a_imag[h * NP + n];
        const float dar = ar * dt;
        const float dai = ai * dt;

        // z^256 = exp(256 * da); reduce phase in revolutions (precise path, once)
        const float e256 = expf(256.0f * dar);
        float rev256 = 256.0f * dai * INV2PI;
        rev256 -= floorf(rev256);
        float s256, c256;
        sincosf(rev256 * TWOPI, &s256, &c256);

        // g = (exp(da) - 1) / a
        const float ed = expf(dar);
        float sd, cd;
        sincosf(dai, &sd, &cd);
        const float emr = ed * cd - 1.0f;
        const float emi = ed * sd;
        const float inv = 1.0f / (ar * ar + ai * ai);
        const float gr  = (emr * ar + emi * ai) * inv;
        const float gi  = (emi * ar - emr * ai) * inv;

        // scaled_c = c * g for both directions
        const float cr0 = coeffs[((0 * H + h) * NP + n) * 2 + 0];
        const float ci0 = coeffs[((0 * H + h) * NP + n) * 2 + 1];
        const float cr1 = coeffs[((1 * H + h) * NP + n) * 2 + 0];
        const float ci1 = coeffs[((1 * H + h) * NP + n) * 2 + 1];

        pole[n * 2 + 0] = make_float4(dar, dai * INV2PI, e256 * c256, e256 * s256);
        pole[n * 2 + 1] = make_float4(cr0 * gr - ci0 * gi,
                                      cr0 * gi + ci0 * gr,
                                      cr1 * gr - ci1 * gi,
                                      cr1 * gi + ci1 * gr);
    }
    __syncthreads();

    float acc0[CHUNK];
    float acc1[CHUNK];
    #pragma unroll
    for (int j = 0; j < CHUNK; ++j) { acc0[j] = 0.0f; acc1[j] = 0.0f; }

    const float lf = (float)t;

    #pragma unroll 1
    for (int n = 0; n < NP; ++n) {
        const float4 p0 = pole[n * 2 + 0];
        const float4 p1 = pole[n * 2 + 1];

        // w = exp(da * t): magnitude + phase (phase < ~400 rev, fp32 OK)
        const float e  = __expf(p0.x * lf);
        float rev = p0.y * lf;
        rev -= floorf(rev);
        float s, c;
        __sincosf(rev * TWOPI, &s, &c);
        float wr = e * c;
        float wi = e * s;

        #pragma unroll
        for (int j = 0; j < CHUNK; ++j) {
            acc0[j] = fmaf(p1.x, wr, fmaf(-p1.y, wi, acc0[j]));
            acc1[j] = fmaf(p1.z, wr, fmaf(-p1.w, wi, acc1[j]));
            // w *= z^256
            const float nwr = fmaf(wr, p0.z, -(wi * p0.w));
            wi              = fmaf(wi, p0.z,  (wr * p0.w));
            wr = nwr;
        }
    }

    float* o0 = out + (size_t)h * L + t;            // dir 0
    float* o1 = out + (size_t)(H + h) * L + t;      // dir 1
    #pragma unroll
    for (int j = 0; j < CHUNK; ++j) {
        o0[j * BLOCK] = 2.0f * acc0[j];
        o1[j * BLOCK] = 2.0f * acc1[j];
    }
}

extern "C" void kernel_launch(void* const* d_in, const int* in_sizes, int n_in,
                              void* d_out, int out_size, void* d_ws, size_t ws_size,
                              hipStream_t stream) {
    const float* log_dt     = (const float*)d_in[0];
    const float* log_a_real = (const float*)d_in[1];
    const float* a_imag     = (const float*)d_in[2];
    const float* coeffs     = (const float*)d_in[3];
    // d_in[4] = sequence_length (== 4096, compile-time constant here)
    float* out = (float*)d_out;

    ssm_vand_kernel<<<dim3(H), dim3(BLOCK), 0, stream>>>(
        log_dt, log_a_real, a_imag, coeffs, out);
}